// Round 3
// baseline (1012.469 us; speedup 1.0000x reference)
//
#include <hip/hip_runtime.h>

// GNNML3: 3x (SpectConv + gated linear) + fc2, N=50k nodes, E=1.6M edges, K=10 supports.
// R3: kill the atomics. Two sorts built once per call:
//   - physical src-sort of ea (sequential XW gather in Phase A)
//   - dst-rank permutation permBA[dst_rank]=src_rank (segment reduce in Phase B)
// Layers 2/3: PhaseA (edge-parallel, streaming, writes M[e,32]) then
//             PhaseB (node-parallel segment sum of M rows, one store per node).
// Layer 1 (CIN=1): fully fused thread-per-node over dst-ordered edges.

constexpr int K  = 10;   // spectral supports
constexpr int C1 = 32;   // conv out
constexpr int C2 = 16;   // gate out
constexpr int CC = 48;   // concat width

// ---------------- sort machinery ----------------
__global__ __launch_bounds__(256)
void hist_kernel(const int* __restrict__ idx, int* __restrict__ hist, int E) {
    int i = blockIdx.x * 256 + threadIdx.x;
    if (i < E) atomicAdd(&hist[idx[i]], 1);
}

// single-block exclusive scan over n histogram entries
__global__ __launch_bounds__(1024)
void scan_kernel(const int* __restrict__ hist, int* __restrict__ offs, int n) {
    __shared__ int sums[1024];
    int t = threadIdx.x;
    int chunk = (n + 1023) >> 10;
    int lo = t * chunk, hi = min(lo + chunk, n);
    int s = 0;
    for (int i = lo; i < hi; ++i) s += hist[i];
    sums[t] = s;
    __syncthreads();
    for (int off = 1; off < 1024; off <<= 1) {
        int addv = (t >= off) ? sums[t - off] : 0;
        __syncthreads();
        sums[t] += addv;
        __syncthreads();
    }
    int run = sums[t] - s;  // exclusive base of this thread's chunk
    for (int i = lo; i < hi; ++i) { offs[i] = run; run += hist[i]; }
}

// physical sort of ea by src; records each edge's src-rank
__global__ __launch_bounds__(256)
void scatter_src_kernel(const float* __restrict__ ea, const int* __restrict__ src,
                        int* __restrict__ offw, float* __restrict__ ea_s,
                        int* __restrict__ src_s, int* __restrict__ srcrank, int E) {
    int e = blockIdx.x * 256 + threadIdx.x;
    if (e >= E) return;
    int s = src[e];
    int pos = atomicAdd(&offw[s], 1);
    src_s[pos] = s;
    srcrank[e] = pos;
    const float2* ep = (const float2*)(ea + (size_t)e * K);
    float2* eo = (float2*)(ea_s + (size_t)pos * K);
#pragma unroll
    for (int k = 0; k < K / 2; ++k) eo[k] = ep[k];
}

// dst-rank pass: permBA[dst_rank] = src_rank, e2o[dst_rank] = original edge id
__global__ __launch_bounds__(256)
void rank_dst_kernel(const int* __restrict__ dst, const int* __restrict__ srcrank,
                     int* __restrict__ offw, int* __restrict__ permBA,
                     int* __restrict__ e2o, int E) {
    int e = blockIdx.x * 256 + threadIdx.x;
    if (e >= E) return;
    int j = atomicAdd(&offw[dst[e]], 1);
    permBA[j] = srcrank[e];
    e2o[j] = e;
}

// ---------------- dense XW = x @ W[k] ----------------
// XW[n,k,c'] = sum_c x[n,c] * W[k,c,c']   (W: [K,CIN,32] row-major)
template<int CIN>
__global__ __launch_bounds__(256)
void xw_kernel(const float* __restrict__ x, const float* __restrict__ W,
               float* __restrict__ XW, int N) {
    __shared__ float Ws[K * CIN * C1];
    for (int i = threadIdx.x; i < K * CIN * C1; i += 256) Ws[i] = W[i];
    __syncthreads();
    int node = blockIdx.x * 8 + (int)(threadIdx.x >> 5);
    int cp   = threadIdx.x & 31;
    if (node >= N) return;
    float xv[CIN];
#pragma unroll
    for (int c = 0; c < CIN; ++c) xv[c] = x[(size_t)node * CIN + c];
#pragma unroll
    for (int k = 0; k < K; ++k) {
        float a = 0.f;
#pragma unroll
        for (int c = 0; c < CIN; ++c) a = fmaf(xv[c], Ws[(k * CIN + c) * C1 + cp], a);
        XW[(size_t)node * (K * C1) + k * C1 + cp] = a;
    }
}

// ---------------- layer 1 fused (CIN=1): h = segsum(ea*x_src); acc = h@W1 ----------------
__global__ __launch_bounds__(256)
void layer1_kernel(const float* __restrict__ x, const float* __restrict__ W1,
                   const float* __restrict__ ea, const int* __restrict__ src,
                   const int* __restrict__ e2o, const int* __restrict__ rowptr,
                   float* __restrict__ acc, int N, int E) {
    __shared__ float Ws[K * C1];
    for (int i = threadIdx.x; i < K * C1; i += 256) Ws[i] = W1[i];
    __syncthreads();
    int n = blockIdx.x * 256 + threadIdx.x;
    if (n >= N) return;
    int lo = rowptr[n];
    int hi = (n + 1 < N) ? rowptr[n + 1] : E;
    float h[K];
#pragma unroll
    for (int k = 0; k < K; ++k) h[k] = 0.f;
    for (int j = lo; j < hi; ++j) {
        int e = e2o[j];
        float xs = x[src[e]];
        const float* ep = ea + (size_t)e * K;
#pragma unroll
        for (int k = 0; k < K; ++k) h[k] = fmaf(ep[k], xs, h[k]);
    }
#pragma unroll
    for (int c = 0; c < C1; ++c) {
        float a = 0.f;
#pragma unroll
        for (int k = 0; k < K; ++k) a = fmaf(h[k], Ws[k * C1 + c], a);
        acc[(size_t)n * C1 + c] = a;
    }
}

// ---------------- Phase A: per-edge message, src-sorted, streaming ----------------
__global__ __launch_bounds__(256)
void phaseA_kernel(const float* __restrict__ XW, const float* __restrict__ ea_s,
                   const int* __restrict__ src_s, float* __restrict__ M, int E) {
    int gid = blockIdx.x * 256 + threadIdx.x;
    int i   = gid >> 5;
    if (i >= E) return;
    int cp = threadIdx.x & 31;
    int s  = src_s[i];
    const float* xw  = XW + (size_t)s * (K * C1) + cp;
    const float* eap = ea_s + (size_t)i * K;
    float m = 0.f;
#pragma unroll
    for (int k = 0; k < K; ++k) m = fmaf(eap[k], xw[k * C1], m);
    M[(size_t)i * C1 + cp] = m;
}

// ---------------- Phase B: dst-segment reduce of M rows, no atomics ----------------
__global__ __launch_bounds__(256)
void phaseB_kernel(const float* __restrict__ M, const int* __restrict__ permBA,
                   const int* __restrict__ rowptr, float* __restrict__ acc,
                   int N, int E) {
    int n  = blockIdx.x * 8 + (int)(threadIdx.x >> 5);
    int cp = threadIdx.x & 31;
    if (n >= N) return;
    int lo = rowptr[n];
    int hi = (n + 1 < N) ? rowptr[n + 1] : E;
    float s = 0.f;
    if (lo < hi) {
        int p = permBA[lo];
        for (int j = lo + 1; j < hi; ++j) {
            int pn = permBA[j];                    // prefetch next rank
            s += M[(size_t)p * C1 + cp];
            p = pn;
        }
        s += M[(size_t)p * C1 + cp];
    }
    acc[(size_t)n * C1 + cp] = s;
}

// ---------------- unsorted-fallback edge kernels (atomic path) ----------------
__global__ __launch_bounds__(256)
void edge1_kernel(const float* __restrict__ x, const float* __restrict__ W1,
                  const float* __restrict__ ea, const int* __restrict__ src,
                  const int* __restrict__ dst, float* __restrict__ acc, int E) {
    __shared__ float Ws[K * C1];
    for (int i = threadIdx.x; i < K * C1; i += 256) Ws[i] = W1[i];
    __syncthreads();
    int gid = blockIdx.x * 256 + threadIdx.x;
    int e   = gid >> 5;
    if (e >= E) return;
    int cp = threadIdx.x & 31;
    float xv = x[src[e]];
    const float* eap = ea + (size_t)e * K;
    float m = 0.f;
#pragma unroll
    for (int k = 0; k < K; ++k) m = fmaf(eap[k], Ws[k * C1 + cp], m);
    atomicAdd(acc + (size_t)dst[e] * C1 + cp, m * xv);
}

__global__ __launch_bounds__(256)
void edge_kernel(const float* __restrict__ XW, const float* __restrict__ ea,
                 const int* __restrict__ src, const int* __restrict__ dst,
                 float* __restrict__ acc, int E) {
    int gid = blockIdx.x * 256 + threadIdx.x;
    int e   = gid >> 5;
    if (e >= E) return;
    int cp = threadIdx.x & 31;
    const float* xw  = XW + (size_t)src[e] * (K * C1) + cp;
    const float* eap = ea + (size_t)e * K;
    float m = 0.f;
#pragma unroll
    for (int k = 0; k < K; ++k) m = fmaf(eap[k], xw[k * C1], m);
    atomicAdd(acc + (size_t)dst[e] * C1 + cp, m);
}

// ---------------- node epilogue ----------------
template<int CIN, bool FINAL>
__global__ __launch_bounds__(256)
void epilogue_kernel(const float* __restrict__ acc, const float* __restrict__ b,
                     const float* __restrict__ x, const float* __restrict__ U,
                     const float* __restrict__ ub, const float* __restrict__ V,
                     const float* __restrict__ vb, float* __restrict__ xnext,
                     const float* __restrict__ fc2w, const float* __restrict__ fc2b,
                     float* __restrict__ out, int N) {
    int node = blockIdx.x * 16 + (int)(threadIdx.x >> 4);
    int cp   = threadIdx.x & 15;
    if (node >= N) return;
    float r0 = acc[(size_t)node * C1 + cp]      + b[cp];
    float r1 = acc[(size_t)node * C1 + 16 + cp] + b[16 + cp];
    r0 = r0 > 0.f ? r0 : 0.f;
    r1 = r1 > 0.f ? r1 : 0.f;
    float u = ub[cp], v = vb[cp];
#pragma unroll
    for (int c = 0; c < CIN; ++c) {
        float xc = x[(size_t)node * CIN + c];
        u = fmaf(xc, U[c * C2 + cp], u);
        v = fmaf(xc, V[c * C2 + cp], v);
    }
    float g = u * v;
    if (!FINAL) {
        xnext[(size_t)node * CC + cp]      = r0;
        xnext[(size_t)node * CC + 16 + cp] = r1;
        xnext[(size_t)node * CC + 32 + cp] = g;
    } else {
        float dp = r0 * fc2w[cp] + r1 * fc2w[16 + cp] + g * fc2w[32 + cp];
#pragma unroll
        for (int off = 8; off; off >>= 1) dp += __shfl_xor(dp, off, 16);
        if (cp == 0) out[node] = dp + fc2b[0];
    }
}

extern "C" void kernel_launch(void* const* d_in, const int* in_sizes, int n_in,
                              void* d_out, int out_size, void* d_ws, size_t ws_size,
                              hipStream_t stream) {
    const float* x   = (const float*)d_in[0];
    const float* ea  = (const float*)d_in[1];
    const int*   ei  = (const int*)d_in[2];
    const int N = in_sizes[0];        // NIN == 1
    const int E = in_sizes[1] / K;
    const int* srcp = ei;
    const int* dstp = ei + E;

    const float *W1 = (const float*)d_in[3],  *b1 = (const float*)d_in[4];
    const float *U1 = (const float*)d_in[5],  *ub1 = (const float*)d_in[6];
    const float *V1 = (const float*)d_in[7],  *vb1 = (const float*)d_in[8];
    const float *W2 = (const float*)d_in[9],  *b2 = (const float*)d_in[10];
    const float *U2 = (const float*)d_in[11], *ub2 = (const float*)d_in[12];
    const float *V2 = (const float*)d_in[13], *vb2 = (const float*)d_in[14];
    const float *W3 = (const float*)d_in[15], *b3 = (const float*)d_in[16];
    const float *U3 = (const float*)d_in[17], *ub3 = (const float*)d_in[18];
    const float *V3 = (const float*)d_in[19], *vb3 = (const float*)d_in[20];
    const float *fc2w = (const float*)d_in[21], *fc2b = (const float*)d_in[22];

    // ---- workspace layout (small/shared buffers first so fallback fits) ----
    float* acc = (float*)d_ws;                    // N*C1           (6.4 MB)
    float* x2  = acc + (size_t)N * C1;            // N*CC           (9.6 MB)
    float* x3  = x2  + (size_t)N * CC;            // N*CC           (9.6 MB)
    float* XW  = x3  + (size_t)N * CC;            // N*K*C1         (64 MB)
    float* M   = XW  + (size_t)N * K * C1;        // E*C1           (204.8 MB)
    float* ea_s = M  + (size_t)E * C1;            // E*K            (64 MB)
    int* src_s   = (int*)(ea_s + (size_t)E * K);  // E
    int* srcrank = src_s + E;                     // E
    int* permBA  = srcrank + E;                   // E
    int* e2o     = permBA + E;                    // E
    int* hist    = e2o + E;                       // N
    int* rowptr  = hist + N;                      // N
    int* offw    = rowptr + N;                    // N
    size_t needFull = (size_t)((char*)(offw + N) - (char*)d_ws);
    size_t needFB   = (size_t)((char*)(M) - (char*)d_ws);
    bool full = ws_size >= needFull;

    const int eBlocks  = (E + 255) / 256;                         // 1 thread/edge
    const int egBlocks = (int)(((size_t)E * 32 + 255) / 256);     // 32 lanes/edge
    const int nBlocks  = (N + 255) / 256;                         // 1 thread/node
    const int ngBlocks = (N + 7) / 8;                             // 32 lanes/node
    const int xwBlocks = (N + 7) / 8;
    const int epBlocks = (N + 15) / 16;
    const size_t accBytes = (size_t)N * C1 * sizeof(float);

    if (full) {
        // ---- build both orders (once per call) ----
        hipMemsetAsync(hist, 0, (size_t)N * sizeof(int), stream);
        hist_kernel<<<eBlocks, 256, 0, stream>>>(srcp, hist, E);
        scan_kernel<<<1, 1024, 0, stream>>>(hist, offw, N);
        scatter_src_kernel<<<eBlocks, 256, 0, stream>>>(ea, srcp, offw,
                                                        ea_s, src_s, srcrank, E);
        hipMemsetAsync(hist, 0, (size_t)N * sizeof(int), stream);
        hist_kernel<<<eBlocks, 256, 0, stream>>>(dstp, hist, E);
        scan_kernel<<<1, 1024, 0, stream>>>(hist, rowptr, N);
        hipMemcpyAsync(offw, rowptr, (size_t)N * sizeof(int),
                       hipMemcpyDeviceToDevice, stream);
        rank_dst_kernel<<<eBlocks, 256, 0, stream>>>(dstp, srcrank, offw,
                                                     permBA, e2o, E);

        // ---- layer 1 (fused, no atomics) ----
        layer1_kernel<<<nBlocks, 256, 0, stream>>>(x, W1, ea, srcp, e2o, rowptr,
                                                   acc, N, E);
        epilogue_kernel<1, false><<<epBlocks, 256, 0, stream>>>(
            acc, b1, x, U1, ub1, V1, vb1, x2, nullptr, nullptr, nullptr, N);

        // ---- layer 2 ----
        xw_kernel<CC><<<xwBlocks, 256, 0, stream>>>(x2, W2, XW, N);
        phaseA_kernel<<<egBlocks, 256, 0, stream>>>(XW, ea_s, src_s, M, E);
        phaseB_kernel<<<ngBlocks, 256, 0, stream>>>(M, permBA, rowptr, acc, N, E);
        epilogue_kernel<CC, false><<<epBlocks, 256, 0, stream>>>(
            acc, b2, x2, U2, ub2, V2, vb2, x3, nullptr, nullptr, nullptr, N);

        // ---- layer 3 (fused fc2) ----
        xw_kernel<CC><<<xwBlocks, 256, 0, stream>>>(x3, W3, XW, N);
        phaseA_kernel<<<egBlocks, 256, 0, stream>>>(XW, ea_s, src_s, M, E);
        phaseB_kernel<<<ngBlocks, 256, 0, stream>>>(M, permBA, rowptr, acc, N, E);
        epilogue_kernel<CC, true><<<epBlocks, 256, 0, stream>>>(
            acc, b3, x3, U3, ub3, V3, vb3, nullptr, fc2w, fc2b, (float*)d_out, N);
    } else {
        // ---- fallback: unsorted atomic path (needs only acc/x2/x3/XW) ----
        (void)needFB;
        hipMemsetAsync(acc, 0, accBytes, stream);
        edge1_kernel<<<egBlocks, 256, 0, stream>>>(x, W1, ea, srcp, dstp, acc, E);
        epilogue_kernel<1, false><<<epBlocks, 256, 0, stream>>>(
            acc, b1, x, U1, ub1, V1, vb1, x2, nullptr, nullptr, nullptr, N);

        hipMemsetAsync(acc, 0, accBytes, stream);
        xw_kernel<CC><<<xwBlocks, 256, 0, stream>>>(x2, W2, XW, N);
        edge_kernel<<<egBlocks, 256, 0, stream>>>(XW, ea, srcp, dstp, acc, E);
        epilogue_kernel<CC, false><<<epBlocks, 256, 0, stream>>>(
            acc, b2, x2, U2, ub2, V2, vb2, x3, nullptr, nullptr, nullptr, N);

        hipMemsetAsync(acc, 0, accBytes, stream);
        xw_kernel<CC><<<xwBlocks, 256, 0, stream>>>(x3, W3, XW, N);
        edge_kernel<<<egBlocks, 256, 0, stream>>>(XW, ea, srcp, dstp, acc, E);
        epilogue_kernel<CC, true><<<epBlocks, 256, 0, stream>>>(
            acc, b3, x3, U3, ub3, V3, vb3, nullptr, fc2w, fc2b, (float*)d_out, N);
    }
}

// Round 4
// 748.633 us; speedup vs baseline: 1.3524x; 1.3524x over previous
//
#include <hip/hip_runtime.h>

// GNNML3 R4: dst-sorted edge stream -> per-node outer-product H[n, k*48+c] in
// registers (10 fma/edge/lane, no atomics) -> bf16 H table -> MFMA GEMM
// [N x 480] @ [480 x 32] -> epilogue. Layer 1 = same path with K padded to 32.

constexpr int K  = 10;   // spectral supports
constexpr int C1 = 32;   // conv out
constexpr int C2 = 16;   // gate out
constexpr int CC = 48;   // concat width

typedef short bf16x8 __attribute__((ext_vector_type(8)));
typedef float f32x4  __attribute__((ext_vector_type(4)));

static __device__ __forceinline__ unsigned short f2bf(float f) {
    unsigned int u = __float_as_uint(f);
    return (unsigned short)((u + 0x7FFFu + ((u >> 16) & 1u)) >> 16);
}

// ---------------- sort machinery (dst only) ----------------
__global__ __launch_bounds__(256)
void hist_kernel(const int* __restrict__ idx, int* __restrict__ hist, int E) {
    int i = blockIdx.x * 256 + threadIdx.x;
    if (i < E) atomicAdd(&hist[idx[i]], 1);
}

__global__ __launch_bounds__(1024)
void scan_kernel(const int* __restrict__ hist, int* __restrict__ offs, int n) {
    __shared__ int sums[1024];
    int t = threadIdx.x;
    int chunk = (n + 1023) >> 10;
    int lo = t * chunk, hi = min(lo + chunk, n);
    int s = 0;
    for (int i = lo; i < hi; ++i) s += hist[i];
    sums[t] = s;
    __syncthreads();
    for (int off = 1; off < 1024; off <<= 1) {
        int addv = (t >= off) ? sums[t - off] : 0;
        __syncthreads();
        sums[t] += addv;
        __syncthreads();
    }
    int run = sums[t] - s;
    for (int i = lo; i < hi; ++i) { offs[i] = run; run += hist[i]; }
}

__global__ __launch_bounds__(256)
void scatter_dst_kernel(const float* __restrict__ ea, const int* __restrict__ src,
                        const int* __restrict__ dst, int* __restrict__ offw,
                        float* __restrict__ ea_d, int* __restrict__ src_d, int E) {
    int e = blockIdx.x * 256 + threadIdx.x;
    if (e >= E) return;
    int pos = atomicAdd(&offw[dst[e]], 1);
    src_d[pos] = src[e];
    const float2* ep = (const float2*)(ea + (size_t)e * K);
    float2* eo = (float2*)(ea_d + (size_t)pos * K);
#pragma unroll
    for (int k = 0; k < K / 2; ++k) eo[k] = ep[k];
}

// ---------------- layer-1 H: H1[n,k] = sum_{e->n} ea[k]*x[src] ----------------
// 16-lane group per node; lane = k. Output [N][32] bf16, slots 10..31 zero.
__global__ __launch_bounds__(256)
void gather1_kernel(const float* __restrict__ x, const float* __restrict__ ea_d,
                    const int* __restrict__ src_d, const int* __restrict__ rowptr,
                    unsigned short* __restrict__ Hb, int N, int E) {
    int n  = blockIdx.x * 16 + (int)(threadIdx.x >> 4);
    int kq = threadIdx.x & 15;
    if (n >= N) return;
    int lo = rowptr[n], hi = (n + 1 < N) ? rowptr[n + 1] : E;
    float h = 0.f;
    for (int j = lo; j < hi; ++j) {
        float eav = (kq < K) ? ea_d[(size_t)j * K + kq] : 0.f;
        float xs  = x[src_d[j]];          // uniform within group -> broadcast
        h = fmaf(eav, xs, h);
    }
    Hb[(size_t)n * 32 + kq]      = (kq < K) ? f2bf(h) : (unsigned short)0;
    Hb[(size_t)n * 32 + 16 + kq] = 0;
}

// ---------------- layers 2/3 H: H[n, k*48+c] outer-product aggregate ----------------
// one wave per node; lane = c (c<48 active); 10 H regs per lane.
__global__ __launch_bounds__(256)
void gather48_kernel(const float* __restrict__ xin, const float* __restrict__ ea_d,
                     const int* __restrict__ src_d, const int* __restrict__ rowptr,
                     unsigned short* __restrict__ Hb, int N, int E) {
    int n = blockIdx.x * 4 + (int)(threadIdx.x >> 6);
    int c = threadIdx.x & 63;
    if (n >= N) return;
    int lo = rowptr[n], hi = (n + 1 < N) ? rowptr[n + 1] : E;
    float H[K];
#pragma unroll
    for (int k = 0; k < K; ++k) H[k] = 0.f;
    for (int j = lo; j < hi; ++j) {
        int s = src_d[j];
        float xs = (c < CC) ? xin[(size_t)s * CC + c] : 0.f;
        const float2* ep = (const float2*)(ea_d + (size_t)j * K);
        float2 e0 = ep[0], e1 = ep[1], e2 = ep[2], e3 = ep[3], e4 = ep[4];
        H[0] = fmaf(e0.x, xs, H[0]); H[1] = fmaf(e0.y, xs, H[1]);
        H[2] = fmaf(e1.x, xs, H[2]); H[3] = fmaf(e1.y, xs, H[3]);
        H[4] = fmaf(e2.x, xs, H[4]); H[5] = fmaf(e2.y, xs, H[5]);
        H[6] = fmaf(e3.x, xs, H[6]); H[7] = fmaf(e3.y, xs, H[7]);
        H[8] = fmaf(e4.x, xs, H[8]); H[9] = fmaf(e4.y, xs, H[9]);
    }
    if (c < CC) {
#pragma unroll
        for (int k = 0; k < K; ++k)
            Hb[(size_t)n * 480 + k * CC + c] = f2bf(H[k]);
    }
}

// ---------------- W -> B-fragment layout (bf16), per mfma_16x16x32 B mapping ----------------
// entry i = (kstep t, half h, lane l): lane holds B[k][col], col=(l&15)+16h,
// k = t*32 + (l>>4)*8 + r, r=0..7 packed contiguously.
__global__ __launch_bounds__(256)
void wconv_kernel(const float* __restrict__ W, unsigned short* __restrict__ Bfrag,
                  int ksteps, int kdact) {
    int i = blockIdx.x * 256 + threadIdx.x;
    if (i >= ksteps * 128) return;
    int t = i >> 7, rem = i & 127, h = rem >> 6, l = rem & 63;
    int cp = (l & 15) + 16 * h;
    int kbase = t * 32 + ((l >> 4) << 3);
    unsigned int pk[4];
#pragma unroll
    for (int q = 0; q < 4; ++q) {
        int kd0 = kbase + 2 * q, kd1 = kbase + 2 * q + 1;
        unsigned int a = (kd0 < kdact) ? f2bf(W[(size_t)kd0 * C1 + cp]) : 0u;
        unsigned int b = (kd1 < kdact) ? f2bf(W[(size_t)kd1 * C1 + cp]) : 0u;
        pk[q] = a | (b << 16);
    }
    uint4 u; u.x = pk[0]; u.y = pk[1]; u.z = pk[2]; u.w = pk[3];
    *(uint4*)(Bfrag + (size_t)i * 8) = u;
}

// ---------------- MFMA GEMM: acc[N x 32] = H[N x KD](bf16) @ Wbig[KD x 32](bf16) ----------------
template<int KSTEPS>
__global__ __launch_bounds__(256)
void hgemm_kernel(const unsigned short* __restrict__ Hb,
                  const unsigned short* __restrict__ Bfrag,
                  float* __restrict__ acc, int N) {
    __shared__ unsigned short Bl[KSTEPS * 2 * 64 * 8];
    for (int i = threadIdx.x; i < KSTEPS * 2 * 64 * 4; i += 256)
        ((unsigned int*)Bl)[i] = ((const unsigned int*)Bfrag)[i];
    __syncthreads();
    int tile = blockIdx.x * 4 + (int)(threadIdx.x >> 6);
    int l = threadIdx.x & 63;
    int node0 = tile * 16;
    if (node0 >= N) return;
    constexpr int KD = KSTEPS * 32;
    int row = l & 15, koff = (l >> 4) * 8;
    f32x4 a0 = {0.f, 0.f, 0.f, 0.f}, a1 = {0.f, 0.f, 0.f, 0.f};
#pragma unroll
    for (int t = 0; t < KSTEPS; ++t) {
        bf16x8 af = *(const bf16x8*)(Hb + (size_t)(node0 + row) * KD + t * 32 + koff);
        bf16x8 b0 = *(const bf16x8*)(&Bl[(t * 2 + 0) * 64 * 8 + l * 8]);
        bf16x8 b1 = *(const bf16x8*)(&Bl[(t * 2 + 1) * 64 * 8 + l * 8]);
        a0 = __builtin_amdgcn_mfma_f32_16x16x32_bf16(af, b0, a0, 0, 0, 0);
        a1 = __builtin_amdgcn_mfma_f32_16x16x32_bf16(af, b1, a1, 0, 0, 0);
    }
    int col = l & 15, rbase = (l >> 4) * 4;
#pragma unroll
    for (int r = 0; r < 4; ++r) {
        int node = node0 + rbase + r;
        acc[(size_t)node * C1 + col]      = a0[r];
        acc[(size_t)node * C1 + 16 + col] = a1[r];
    }
}

// ---------------- node epilogue ----------------
template<int CIN, bool FINAL>
__global__ __launch_bounds__(256)
void epilogue_kernel(const float* __restrict__ acc, const float* __restrict__ b,
                     const float* __restrict__ x, const float* __restrict__ U,
                     const float* __restrict__ ub, const float* __restrict__ V,
                     const float* __restrict__ vb, float* __restrict__ xnext,
                     const float* __restrict__ fc2w, const float* __restrict__ fc2b,
                     float* __restrict__ out, int N) {
    int node = blockIdx.x * 16 + (int)(threadIdx.x >> 4);
    int cp   = threadIdx.x & 15;
    if (node >= N) return;
    float r0 = acc[(size_t)node * C1 + cp]      + b[cp];
    float r1 = acc[(size_t)node * C1 + 16 + cp] + b[16 + cp];
    r0 = r0 > 0.f ? r0 : 0.f;
    r1 = r1 > 0.f ? r1 : 0.f;
    float u = ub[cp], v = vb[cp];
#pragma unroll
    for (int c = 0; c < CIN; ++c) {
        float xc = x[(size_t)node * CIN + c];
        u = fmaf(xc, U[c * C2 + cp], u);
        v = fmaf(xc, V[c * C2 + cp], v);
    }
    float g = u * v;
    if (!FINAL) {
        xnext[(size_t)node * CC + cp]      = r0;
        xnext[(size_t)node * CC + 16 + cp] = r1;
        xnext[(size_t)node * CC + 32 + cp] = g;
    } else {
        float dp = r0 * fc2w[cp] + r1 * fc2w[16 + cp] + g * fc2w[32 + cp];
#pragma unroll
        for (int off = 8; off; off >>= 1) dp += __shfl_xor(dp, off, 16);
        if (cp == 0) out[node] = dp + fc2b[0];
    }
}

// ---------------- fallback (atomic path, ws-too-small insurance) ----------------
__global__ __launch_bounds__(256)
void edge1_kernel(const float* __restrict__ x, const float* __restrict__ W1,
                  const float* __restrict__ ea, const int* __restrict__ src,
                  const int* __restrict__ dst, float* __restrict__ acc, int E) {
    __shared__ float Ws[K * C1];
    for (int i = threadIdx.x; i < K * C1; i += 256) Ws[i] = W1[i];
    __syncthreads();
    int gid = blockIdx.x * 256 + threadIdx.x;
    int e = gid >> 5;
    if (e >= E) return;
    int cp = threadIdx.x & 31;
    float xv = x[src[e]];
    const float* eap = ea + (size_t)e * K;
    float m = 0.f;
#pragma unroll
    for (int k = 0; k < K; ++k) m = fmaf(eap[k], Ws[k * C1 + cp], m);
    atomicAdd(acc + (size_t)dst[e] * C1 + cp, m * xv);
}

template<int CIN>
__global__ __launch_bounds__(256)
void xw_kernel(const float* __restrict__ x, const float* __restrict__ W,
               float* __restrict__ XW, int N) {
    __shared__ float Ws[K * CIN * C1];
    for (int i = threadIdx.x; i < K * CIN * C1; i += 256) Ws[i] = W[i];
    __syncthreads();
    int node = blockIdx.x * 8 + (int)(threadIdx.x >> 5);
    int cp = threadIdx.x & 31;
    if (node >= N) return;
    float xv[CIN];
#pragma unroll
    for (int c = 0; c < CIN; ++c) xv[c] = x[(size_t)node * CIN + c];
#pragma unroll
    for (int k = 0; k < K; ++k) {
        float a = 0.f;
#pragma unroll
        for (int c = 0; c < CIN; ++c) a = fmaf(xv[c], Ws[(k * CIN + c) * C1 + cp], a);
        XW[(size_t)node * (K * C1) + k * C1 + cp] = a;
    }
}

__global__ __launch_bounds__(256)
void edge_kernel(const float* __restrict__ XW, const float* __restrict__ ea,
                 const int* __restrict__ src, const int* __restrict__ dst,
                 float* __restrict__ acc, int E) {
    int gid = blockIdx.x * 256 + threadIdx.x;
    int e = gid >> 5;
    if (e >= E) return;
    int cp = threadIdx.x & 31;
    const float* xw = XW + (size_t)src[e] * (K * C1) + cp;
    const float* eap = ea + (size_t)e * K;
    float m = 0.f;
#pragma unroll
    for (int k = 0; k < K; ++k) m = fmaf(eap[k], xw[k * C1], m);
    atomicAdd(acc + (size_t)dst[e] * C1 + cp, m);
}

extern "C" void kernel_launch(void* const* d_in, const int* in_sizes, int n_in,
                              void* d_out, int out_size, void* d_ws, size_t ws_size,
                              hipStream_t stream) {
    const float* x  = (const float*)d_in[0];
    const float* ea = (const float*)d_in[1];
    const int*   ei = (const int*)d_in[2];
    const int N = in_sizes[0];      // NIN == 1
    const int E = in_sizes[1] / K;
    const int* srcp = ei;
    const int* dstp = ei + E;

    const float *W1 = (const float*)d_in[3],  *b1 = (const float*)d_in[4];
    const float *U1 = (const float*)d_in[5],  *ub1 = (const float*)d_in[6];
    const float *V1 = (const float*)d_in[7],  *vb1 = (const float*)d_in[8];
    const float *W2 = (const float*)d_in[9],  *b2 = (const float*)d_in[10];
    const float *U2 = (const float*)d_in[11], *ub2 = (const float*)d_in[12];
    const float *V2 = (const float*)d_in[13], *vb2 = (const float*)d_in[14];
    const float *W3 = (const float*)d_in[15], *b3 = (const float*)d_in[16];
    const float *U3 = (const float*)d_in[17], *ub3 = (const float*)d_in[18];
    const float *V3 = (const float*)d_in[19], *vb3 = (const float*)d_in[20];
    const float *fc2w = (const float*)d_in[21], *fc2b = (const float*)d_in[22];

    // ---- workspace layout ----
    float* acc = (float*)d_ws;                        // N*C1      (6.4 MB)
    float* x2  = acc + (size_t)N * C1;                // N*CC      (9.6 MB)
    float* x3  = x2  + (size_t)N * CC;                // N*CC      (9.6 MB)
    float* ea_d = x3 + (size_t)N * CC;                // E*K       (64 MB)   [fallback: XW]
    int*   src_d = (int*)(ea_d + (size_t)E * K);      // E         (6.4 MB)
    unsigned short* Hb    = (unsigned short*)(src_d + E);   // N*480 bf16 (48 MB)
    unsigned short* Bfrag = Hb + (size_t)N * 480;           // 15*2*64*8  (30 KB)
    unsigned short* Bfrg1 = Bfrag + 15 * 2 * 64 * 8;        // 1*2*64*8   (2 KB)
    int* hist   = (int*)(Bfrg1 + 2 * 64 * 8);         // N
    int* rowptr = hist + N;                           // N
    int* offw   = rowptr + N;                         // N
    size_t needMain = (size_t)((char*)(offw + N) - (char*)d_ws);
    bool mainPath = ws_size >= needMain;

    const int eBlocks   = (E + 255) / 256;
    const int g1Blocks  = (N + 15) / 16;
    const int g48Blocks = (N + 3) / 4;
    const int tiles     = (N + 15) / 16;
    const int gmBlocks  = (tiles + 3) / 4;
    const int epBlocks  = (N + 15) / 16;

    if (mainPath) {
        // ---- dst-sort (once per call) ----
        hipMemsetAsync(hist, 0, (size_t)N * sizeof(int), stream);
        hist_kernel<<<eBlocks, 256, 0, stream>>>(dstp, hist, E);
        scan_kernel<<<1, 1024, 0, stream>>>(hist, rowptr, N);
        hipMemcpyAsync(offw, rowptr, (size_t)N * sizeof(int),
                       hipMemcpyDeviceToDevice, stream);
        scatter_dst_kernel<<<eBlocks, 256, 0, stream>>>(ea, srcp, dstp, offw,
                                                        ea_d, src_d, E);

        // ---- layer 1 ----
        wconv_kernel<<<1, 256, 0, stream>>>(W1, Bfrg1, 1, K);
        gather1_kernel<<<g1Blocks, 256, 0, stream>>>(x, ea_d, src_d, rowptr, Hb, N, E);
        hgemm_kernel<1><<<gmBlocks, 256, 0, stream>>>(Hb, Bfrg1, acc, N);
        epilogue_kernel<1, false><<<epBlocks, 256, 0, stream>>>(
            acc, b1, x, U1, ub1, V1, vb1, x2, nullptr, nullptr, nullptr, N);

        // ---- layer 2 ----
        gather48_kernel<<<g48Blocks, 256, 0, stream>>>(x2, ea_d, src_d, rowptr, Hb, N, E);
        wconv_kernel<<<8, 256, 0, stream>>>(W2, Bfrag, 15, 480);
        hgemm_kernel<15><<<gmBlocks, 256, 0, stream>>>(Hb, Bfrag, acc, N);
        epilogue_kernel<CC, false><<<epBlocks, 256, 0, stream>>>(
            acc, b2, x2, U2, ub2, V2, vb2, x3, nullptr, nullptr, nullptr, N);

        // ---- layer 3 ----
        gather48_kernel<<<g48Blocks, 256, 0, stream>>>(x3, ea_d, src_d, rowptr, Hb, N, E);
        wconv_kernel<<<8, 256, 0, stream>>>(W3, Bfrag, 15, 480);
        hgemm_kernel<15><<<gmBlocks, 256, 0, stream>>>(Hb, Bfrag, acc, N);
        epilogue_kernel<CC, true><<<epBlocks, 256, 0, stream>>>(
            acc, b3, x3, U3, ub3, V3, vb3, nullptr, fc2w, fc2b, (float*)d_out, N);
    } else {
        // ---- fallback: unsorted atomic path ----
        float* XW = ea_d;  // reuse region (N*K*C1 = 64 MB)
        const int egBlocks = (int)(((size_t)E * 32 + 255) / 256);
        const int xwBlocks = (N + 7) / 8;
        const size_t accBytes = (size_t)N * C1 * sizeof(float);

        hipMemsetAsync(acc, 0, accBytes, stream);
        edge1_kernel<<<egBlocks, 256, 0, stream>>>(x, W1, ea, srcp, dstp, acc, E);
        epilogue_kernel<1, false><<<epBlocks, 256, 0, stream>>>(
            acc, b1, x, U1, ub1, V1, vb1, x2, nullptr, nullptr, nullptr, N);

        hipMemsetAsync(acc, 0, accBytes, stream);
        xw_kernel<CC><<<xwBlocks, 256, 0, stream>>>(x2, W2, XW, N);
        edge_kernel<<<egBlocks, 256, 0, stream>>>(XW, ea, srcp, dstp, acc, E);
        epilogue_kernel<CC, false><<<epBlocks, 256, 0, stream>>>(
            acc, b2, x2, U2, ub2, V2, vb2, x3, nullptr, nullptr, nullptr, N);

        hipMemsetAsync(acc, 0, accBytes, stream);
        xw_kernel<CC><<<xwBlocks, 256, 0, stream>>>(x3, W3, XW, N);
        edge_kernel<<<egBlocks, 256, 0, stream>>>(XW, ea, srcp, dstp, acc, E);
        epilogue_kernel<CC, true><<<epBlocks, 256, 0, stream>>>(
            acc, b3, x3, U3, ub3, V3, vb3, nullptr, fc2w, fc2b, (float*)d_out, N);
    }
}

// Round 5
// 472.073 us; speedup vs baseline: 2.1447x; 1.5858x over previous
//
#include <hip/hip_runtime.h>

// GNNML3 R5: dst-sorted edges; per-node H[k,c] aggregation done with MFMA:
//   A = ea^T planes (bf16, 16B contiguous loads), B = gathered bf16 x rows
//   (4.8MB table, L2-resident), 32-edge chunks, 3 col-groups of 16.
// Then Hb[N x 480](bf16, kd=c*10+k) @ Wbig[480 x 32](bf16) via MFMA (hgemm).
// Layer 1 (CIN=1): wave-per-node scalar gather (4 edges in flight) + hgemm<1>.

constexpr int K  = 10;   // spectral supports
constexpr int C1 = 32;   // conv out
constexpr int C2 = 16;   // gate out
constexpr int CC = 48;   // concat width
constexpr int KD = 480;  // kd = c*10 + k
constexpr int KSTEPS = 15;

typedef short bf16x8 __attribute__((ext_vector_type(8)));
typedef float f32x4  __attribute__((ext_vector_type(4)));
typedef unsigned int uintx4 __attribute__((ext_vector_type(4)));

static __device__ __forceinline__ unsigned short f2bf(float f) {
    unsigned int u = __float_as_uint(f);
    return (unsigned short)((u + 0x7FFFu + ((u >> 16) & 1u)) >> 16);
}
static __device__ __forceinline__ float bf2f(unsigned short h) {
    return __uint_as_float(((unsigned int)h) << 16);
}

// ---------------- sort machinery (dst only) ----------------
__global__ __launch_bounds__(256)
void hist_kernel(const int* __restrict__ idx, int* __restrict__ hist, int E) {
    int i = blockIdx.x * 256 + threadIdx.x;
    if (i < E) atomicAdd(&hist[idx[i]], 1);
}

__global__ __launch_bounds__(1024)
void scan_kernel(const int* __restrict__ hist, int* __restrict__ offs, int n) {
    __shared__ int sums[1024];
    int t = threadIdx.x;
    int chunk = (n + 1023) >> 10;
    int lo = t * chunk, hi = min(lo + chunk, n);
    int s = 0;
    for (int i = lo; i < hi; ++i) s += hist[i];
    sums[t] = s;
    __syncthreads();
    for (int off = 1; off < 1024; off <<= 1) {
        int addv = (t >= off) ? sums[t - off] : 0;
        __syncthreads();
        sums[t] += addv;
        __syncthreads();
    }
    int run = sums[t] - s;
    for (int i = lo; i < hi; ++i) { offs[i] = run; run += hist[i]; }
}

// rank-scatter: ea -> bf16 rank-ordered ea_d[E][10]; src_d[rank]
__global__ __launch_bounds__(256)
void scatter_dst_kernel(const float* __restrict__ ea, const int* __restrict__ src,
                        const int* __restrict__ dst, int* __restrict__ offw,
                        unsigned short* __restrict__ ea_d, int* __restrict__ src_d,
                        int E) {
    int e = blockIdx.x * 256 + threadIdx.x;
    if (e >= E) return;
    int pos = atomicAdd(&offw[dst[e]], 1);
    src_d[pos] = src[e];
    const float2* ep = (const float2*)(ea + (size_t)e * K);
    unsigned int* eo = (unsigned int*)(ea_d + (size_t)pos * K);
#pragma unroll
    for (int q = 0; q < 5; ++q) {
        float2 a = ep[q];
        eo[q] = (unsigned int)f2bf(a.x) | ((unsigned int)f2bf(a.y) << 16);
    }
}

// ea_d [E][10] -> 10 planes ea_t[k][Epad] (coalesced write per plane)
__global__ __launch_bounds__(256)
void transpose_kernel(const unsigned short* __restrict__ ea_d,
                      unsigned short* __restrict__ ea_t, int E, int Epad) {
    int e = blockIdx.x * 256 + threadIdx.x;
    if (e >= E) return;
    const unsigned int* ep = (const unsigned int*)(ea_d + (size_t)e * K);
#pragma unroll
    for (int q = 0; q < 5; ++q) {
        unsigned int u = ep[q];
        ea_t[(size_t)(2 * q)     * Epad + e] = (unsigned short)(u & 0xffffu);
        ea_t[(size_t)(2 * q + 1) * Epad + e] = (unsigned short)(u >> 16);
    }
}

// ---------------- layer-1 gather: wave per node, 4 edges in flight ----------------
__global__ __launch_bounds__(256)
void gather1_kernel(const float* __restrict__ x, const unsigned short* __restrict__ ea_d,
                    const int* __restrict__ src_d, const int* __restrict__ rowptr,
                    unsigned short* __restrict__ Hb, int N, int E) {
    int n = blockIdx.x * 4 + (int)(threadIdx.x >> 6);
    if (n >= N) return;
    int l = threadIdx.x & 63;
    int g = l >> 4, k = l & 15;
    int lo = rowptr[n], hi = (n + 1 < N) ? rowptr[n + 1] : E;
    float h = 0.f;
    for (int j = lo; j < hi; j += 4) {
        int e = j + g;
        bool v = e < hi;
        int s = v ? src_d[e] : 0;
        float xs = v ? x[s] : 0.f;
        float eav = (v && k < K) ? bf2f(ea_d[(size_t)e * K + k]) : 0.f;
        h = fmaf(eav, xs, h);
    }
    h += __shfl_xor(h, 16);
    h += __shfl_xor(h, 32);
    if (l < 32) Hb[(size_t)n * 32 + l] = (l < K) ? f2bf(h) : (unsigned short)0;
}

// ---------------- layers 2/3: MFMA H-aggregation ----------------
// wave per node; A = ea_t rows (k), B = gathered xb rows (32-edge chunk), 3 colgroups
__global__ __launch_bounds__(256)
void gatherM_kernel(const unsigned short* __restrict__ xb,
                    const unsigned short* __restrict__ ea_t,
                    const int* __restrict__ src_d, const int* __restrict__ rowptr,
                    unsigned short* __restrict__ Hb, int N, int E, int Epad) {
    int n = blockIdx.x * 4 + (int)(threadIdx.x >> 6);
    if (n >= N) return;
    int l = threadIdx.x & 63;
    int lo = rowptr[n], hi = (n + 1 < N) ? rowptr[n + 1] : E;
    int row = l & 15;
    int eoff = (l >> 4) * 8;
    const unsigned short* aplane = ea_t + (size_t)row * Epad;
    f32x4 d0 = {0.f,0.f,0.f,0.f}, d1 = {0.f,0.f,0.f,0.f}, d2 = {0.f,0.f,0.f,0.f};
    for (int base = (lo & ~31); base < hi; base += 32) {
        int e0 = base + eoff;
        bf16x8 af = {0,0,0,0,0,0,0,0};
        if (row < K) af = *(const bf16x8*)(aplane + e0);     // 16B aligned
        int4 sA = *(const int4*)(src_d + e0);                // 32B aligned
        int4 sB = *(const int4*)(src_d + e0 + 4);
        int s0 = sA.x, s1 = sA.y, s2 = sA.z, s3 = sA.w;
        int s4 = sB.x, s5 = sB.y, s6 = sB.z, s7 = sB.w;
        unsigned int m0,m1,m2,m3,m4,m5,m6,m7;
#define MSK(r, sv, mv) { int e = e0 + r; bool v = (e >= lo) && (e < hi); \
                         mv = v ? 0xffffffffu : 0u; sv = v ? sv : 0; }
        MSK(0,s0,m0) MSK(1,s1,m1) MSK(2,s2,m2) MSK(3,s3,m3)
        MSK(4,s4,m4) MSK(5,s5,m5) MSK(6,s6,m6) MSK(7,s7,m7)
#undef MSK
        unsigned int bw0[4], bw1[4], bw2[4];
#define GPAIR(q, sa, sb, ma, mb) { \
        const unsigned short* pa = xb + (size_t)sa * CC + row; \
        const unsigned short* pb = xb + (size_t)sb * CC + row; \
        bw0[q] = ((unsigned int)pa[0]  & ma) | (((unsigned int)pb[0]  & mb) << 16); \
        bw1[q] = ((unsigned int)pa[16] & ma) | (((unsigned int)pb[16] & mb) << 16); \
        bw2[q] = ((unsigned int)pa[32] & ma) | (((unsigned int)pb[32] & mb) << 16); }
        GPAIR(0, s0, s1, m0, m1)
        GPAIR(1, s2, s3, m2, m3)
        GPAIR(2, s4, s5, m4, m5)
        GPAIR(3, s6, s7, m6, m7)
#undef GPAIR
        uintx4 u0 = {bw0[0], bw0[1], bw0[2], bw0[3]};
        uintx4 u1 = {bw1[0], bw1[1], bw1[2], bw1[3]};
        uintx4 u2 = {bw2[0], bw2[1], bw2[2], bw2[3]};
        d0 = __builtin_amdgcn_mfma_f32_16x16x32_bf16(af, __builtin_bit_cast(bf16x8, u0), d0, 0, 0, 0);
        d1 = __builtin_amdgcn_mfma_f32_16x16x32_bf16(af, __builtin_bit_cast(bf16x8, u1), d1, 0, 0, 0);
        d2 = __builtin_amdgcn_mfma_f32_16x16x32_bf16(af, __builtin_bit_cast(bf16x8, u2), d2, 0, 0, 0);
    }
    // store H[k=rb..][c] at Hb[n*480 + c*10 + k]  (dword-aligned pairs)
    int rb = (l >> 4) * 4;
    if (rb < K) {
#define STORE_CG(dv, cg) { \
        size_t off = (size_t)n * KD + (size_t)((cg) * 16 + row) * K + rb; \
        *(unsigned int*)(Hb + off) = (unsigned int)f2bf(dv[0]) | ((unsigned int)f2bf(dv[1]) << 16); \
        if (rb != 8) \
            *(unsigned int*)(Hb + off + 2) = (unsigned int)f2bf(dv[2]) | ((unsigned int)f2bf(dv[3]) << 16); }
        STORE_CG(d0, 0) STORE_CG(d1, 1) STORE_CG(d2, 2)
#undef STORE_CG
    }
}

// ---------------- W -> B-fragment (kd = c*10 + k) ----------------
__global__ __launch_bounds__(256)
void wconv_kernel(const float* __restrict__ W, unsigned short* __restrict__ Bfrag,
                  int ksteps, int kdact, int cin) {
    int i = blockIdx.x * 256 + threadIdx.x;
    if (i >= ksteps * 128) return;
    int t = i >> 7, rem = i & 127, h = rem >> 6, l = rem & 63;
    int cp = (l & 15) + 16 * h;
    int kbase = t * 32 + ((l >> 4) << 3);
    unsigned int pk[4];
#pragma unroll
    for (int q = 0; q < 4; ++q) {
        unsigned int a = 0, b = 0;
        int kd0 = kbase + 2 * q, kd1 = kd0 + 1;
        if (kd0 < kdact) { int c = kd0 / K, k = kd0 % K; a = f2bf(W[((size_t)k * cin + c) * C1 + cp]); }
        if (kd1 < kdact) { int c = kd1 / K, k = kd1 % K; b = f2bf(W[((size_t)k * cin + c) * C1 + cp]); }
        pk[q] = a | (b << 16);
    }
    uint4 u; u.x = pk[0]; u.y = pk[1]; u.z = pk[2]; u.w = pk[3];
    *(uint4*)(Bfrag + (size_t)i * 8) = u;
}

// ---------------- MFMA GEMM: acc[N x 32] = Hb[N x KD] @ Wbig ----------------
template<int KS>
__global__ __launch_bounds__(256)
void hgemm_kernel(const unsigned short* __restrict__ Hb,
                  const unsigned short* __restrict__ Bfrag,
                  float* __restrict__ acc, int N) {
    __shared__ unsigned short Bl[KS * 2 * 64 * 8];
    for (int i = threadIdx.x; i < KS * 2 * 64 * 4; i += 256)
        ((unsigned int*)Bl)[i] = ((const unsigned int*)Bfrag)[i];
    __syncthreads();
    int tile = blockIdx.x * 4 + (int)(threadIdx.x >> 6);
    int l = threadIdx.x & 63;
    int node0 = tile * 16;
    if (node0 >= N) return;
    constexpr int KDl = KS * 32;
    int row = l & 15, koff = (l >> 4) * 8;
    f32x4 a0 = {0.f,0.f,0.f,0.f}, a1 = {0.f,0.f,0.f,0.f};
#pragma unroll
    for (int t = 0; t < KS; ++t) {
        bf16x8 af = *(const bf16x8*)(Hb + (size_t)(node0 + row) * KDl + t * 32 + koff);
        bf16x8 b0 = *(const bf16x8*)(&Bl[(t * 2 + 0) * 64 * 8 + l * 8]);
        bf16x8 b1 = *(const bf16x8*)(&Bl[(t * 2 + 1) * 64 * 8 + l * 8]);
        a0 = __builtin_amdgcn_mfma_f32_16x16x32_bf16(af, b0, a0, 0, 0, 0);
        a1 = __builtin_amdgcn_mfma_f32_16x16x32_bf16(af, b1, a1, 0, 0, 0);
    }
    int col = l & 15, rbase = (l >> 4) * 4;
#pragma unroll
    for (int r = 0; r < 4; ++r) {
        int node = node0 + rbase + r;
        acc[(size_t)node * C1 + col]      = a0[r];
        acc[(size_t)node * C1 + 16 + col] = a1[r];
    }
}

// ---------------- node epilogue (emits f32 + bf16 xnext) ----------------
template<int CIN, bool FINAL>
__global__ __launch_bounds__(256)
void epilogue_kernel(const float* __restrict__ acc, const float* __restrict__ b,
                     const float* __restrict__ x, const float* __restrict__ U,
                     const float* __restrict__ ub, const float* __restrict__ V,
                     const float* __restrict__ vb, float* __restrict__ xnext,
                     unsigned short* __restrict__ xbnext,
                     const float* __restrict__ fc2w, const float* __restrict__ fc2b,
                     float* __restrict__ out, int N) {
    int node = blockIdx.x * 16 + (int)(threadIdx.x >> 4);
    int cp   = threadIdx.x & 15;
    if (node >= N) return;
    float r0 = acc[(size_t)node * C1 + cp]      + b[cp];
    float r1 = acc[(size_t)node * C1 + 16 + cp] + b[16 + cp];
    r0 = r0 > 0.f ? r0 : 0.f;
    r1 = r1 > 0.f ? r1 : 0.f;
    float u = ub[cp], v = vb[cp];
#pragma unroll
    for (int c = 0; c < CIN; ++c) {
        float xc = x[(size_t)node * CIN + c];
        u = fmaf(xc, U[c * C2 + cp], u);
        v = fmaf(xc, V[c * C2 + cp], v);
    }
    float g = u * v;
    if (!FINAL) {
        xnext[(size_t)node * CC + cp]      = r0;
        xnext[(size_t)node * CC + 16 + cp] = r1;
        xnext[(size_t)node * CC + 32 + cp] = g;
        xbnext[(size_t)node * CC + cp]      = f2bf(r0);
        xbnext[(size_t)node * CC + 16 + cp] = f2bf(r1);
        xbnext[(size_t)node * CC + 32 + cp] = f2bf(g);
    } else {
        float dp = r0 * fc2w[cp] + r1 * fc2w[16 + cp] + g * fc2w[32 + cp];
#pragma unroll
        for (int off = 8; off; off >>= 1) dp += __shfl_xor(dp, off, 16);
        if (cp == 0) out[node] = dp + fc2b[0];
    }
}

// ---------------- fallback (atomic path) ----------------
__global__ __launch_bounds__(256)
void edge1_kernel(const float* __restrict__ x, const float* __restrict__ W1,
                  const float* __restrict__ ea, const int* __restrict__ src,
                  const int* __restrict__ dst, float* __restrict__ acc, int E) {
    __shared__ float Ws[K * C1];
    for (int i = threadIdx.x; i < K * C1; i += 256) Ws[i] = W1[i];
    __syncthreads();
    int gid = blockIdx.x * 256 + threadIdx.x;
    int e = gid >> 5;
    if (e >= E) return;
    int cp = threadIdx.x & 31;
    float xv = x[src[e]];
    const float* eap = ea + (size_t)e * K;
    float m = 0.f;
#pragma unroll
    for (int k = 0; k < K; ++k) m = fmaf(eap[k], Ws[k * C1 + cp], m);
    atomicAdd(acc + (size_t)dst[e] * C1 + cp, m * xv);
}

template<int CIN>
__global__ __launch_bounds__(256)
void xw_kernel(const float* __restrict__ x, const float* __restrict__ W,
               float* __restrict__ XW, int N) {
    __shared__ float Ws[K * CIN * C1];
    for (int i = threadIdx.x; i < K * CIN * C1; i += 256) Ws[i] = W[i];
    __syncthreads();
    int node = blockIdx.x * 8 + (int)(threadIdx.x >> 5);
    int cp = threadIdx.x & 31;
    if (node >= N) return;
    float xv[CIN];
#pragma unroll
    for (int c = 0; c < CIN; ++c) xv[c] = x[(size_t)node * CIN + c];
#pragma unroll
    for (int k = 0; k < K; ++k) {
        float a = 0.f;
#pragma unroll
        for (int c = 0; c < CIN; ++c) a = fmaf(xv[c], Ws[(k * CIN + c) * C1 + cp], a);
        XW[(size_t)node * (K * C1) + k * C1 + cp] = a;
    }
}

__global__ __launch_bounds__(256)
void edge_kernel(const float* __restrict__ XW, const float* __restrict__ ea,
                 const int* __restrict__ src, const int* __restrict__ dst,
                 float* __restrict__ acc, int E) {
    int gid = blockIdx.x * 256 + threadIdx.x;
    int e = gid >> 5;
    if (e >= E) return;
    int cp = threadIdx.x & 31;
    const float* xw = XW + (size_t)src[e] * (K * C1) + cp;
    const float* eap = ea + (size_t)e * K;
    float m = 0.f;
#pragma unroll
    for (int k = 0; k < K; ++k) m = fmaf(eap[k], xw[k * C1], m);
    atomicAdd(acc + (size_t)dst[e] * C1 + cp, m);
}

extern "C" void kernel_launch(void* const* d_in, const int* in_sizes, int n_in,
                              void* d_out, int out_size, void* d_ws, size_t ws_size,
                              hipStream_t stream) {
    const float* x  = (const float*)d_in[0];
    const float* ea = (const float*)d_in[1];
    const int*   ei = (const int*)d_in[2];
    const int N = in_sizes[0];      // NIN == 1
    const int E = in_sizes[1] / K;
    const int Epad = ((E + 31) & ~31) + 32;
    const int* srcp = ei;
    const int* dstp = ei + E;

    const float *W1 = (const float*)d_in[3],  *b1 = (const float*)d_in[4];
    const float *U1 = (const float*)d_in[5],  *ub1 = (const float*)d_in[6];
    const float *V1 = (const float*)d_in[7],  *vb1 = (const float*)d_in[8];
    const float *W2 = (const float*)d_in[9],  *b2 = (const float*)d_in[10];
    const float *U2 = (const float*)d_in[11], *ub2 = (const float*)d_in[12];
    const float *V2 = (const float*)d_in[13], *vb2 = (const float*)d_in[14];
    const float *W3 = (const float*)d_in[15], *b3 = (const float*)d_in[16];
    const float *U3 = (const float*)d_in[17], *ub3 = (const float*)d_in[18];
    const float *V3 = (const float*)d_in[19], *vb3 = (const float*)d_in[20];
    const float *fc2w = (const float*)d_in[21], *fc2b = (const float*)d_in[22];

    // ---- workspace layout ----
    float* acc = (float*)d_ws;                             // N*32 f32   (6.4 MB)
    float* x2  = acc + (size_t)N * C1;                     // N*48 f32   (9.6 MB)
    float* x3  = x2  + (size_t)N * CC;                     // N*48 f32   (9.6 MB)
    unsigned short* xb2 = (unsigned short*)(x3 + (size_t)N * CC);  // N*48 bf16 (4.8 MB)
    unsigned short* xb3 = xb2 + (size_t)N * CC;            // N*48 bf16  (4.8 MB)
    unsigned short* ea_d = xb3 + (size_t)N * CC;           // E*10 bf16  (32 MB)
    unsigned short* ea_t = ea_d + (size_t)E * K;           // 10*Epad    (32 MB)
    int* src_d = (int*)(ea_t + (size_t)K * Epad);          // Epad       (6.4 MB)
    unsigned short* Hb    = (unsigned short*)(src_d + Epad); // N*480    (48 MB)
    unsigned short* Bfrag = Hb + (size_t)N * KD;           // 15*1024
    unsigned short* Bfrg1 = Bfrag + KSTEPS * 2 * 64 * 8;   // 1024
    int* hist   = (int*)(Bfrg1 + 2 * 64 * 8);              // N
    int* rowptr = hist + N;                                // N
    int* offw   = rowptr + N;                              // N
    size_t needMain = (size_t)((char*)(offw + N) - (char*)d_ws);
    bool mainPath = ws_size >= needMain;

    const int eBlocks  = (E + 255) / 256;
    const int nwBlocks = (N + 3) / 4;                      // wave per node
    const int tiles    = (N + 15) / 16;
    const int gmBlocks = (tiles + 3) / 4;
    const int epBlocks = (N + 15) / 16;

    if (mainPath) {
        // ---- sort + transpose (once per call) ----
        hipMemsetAsync(hist, 0, (size_t)N * sizeof(int), stream);
        hist_kernel<<<eBlocks, 256, 0, stream>>>(dstp, hist, E);
        scan_kernel<<<1, 1024, 0, stream>>>(hist, rowptr, N);
        hipMemcpyAsync(offw, rowptr, (size_t)N * sizeof(int),
                       hipMemcpyDeviceToDevice, stream);
        scatter_dst_kernel<<<eBlocks, 256, 0, stream>>>(ea, srcp, dstp, offw,
                                                        ea_d, src_d, E);
        transpose_kernel<<<eBlocks, 256, 0, stream>>>(ea_d, ea_t, E, Epad);

        // ---- layer 1 ----
        wconv_kernel<<<1, 256, 0, stream>>>(W1, Bfrg1, 1, K, 1);
        gather1_kernel<<<nwBlocks, 256, 0, stream>>>(x, ea_d, src_d, rowptr, Hb, N, E);
        hgemm_kernel<1><<<gmBlocks, 256, 0, stream>>>(Hb, Bfrg1, acc, N);
        epilogue_kernel<1, false><<<epBlocks, 256, 0, stream>>>(
            acc, b1, x, U1, ub1, V1, vb1, x2, xb2, nullptr, nullptr, nullptr, N);

        // ---- layer 2 ----
        gatherM_kernel<<<nwBlocks, 256, 0, stream>>>(xb2, ea_t, src_d, rowptr, Hb, N, E, Epad);
        wconv_kernel<<<8, 256, 0, stream>>>(W2, Bfrag, KSTEPS, KD, CC);
        hgemm_kernel<KSTEPS><<<gmBlocks, 256, 0, stream>>>(Hb, Bfrag, acc, N);
        epilogue_kernel<CC, false><<<epBlocks, 256, 0, stream>>>(
            acc, b2, x2, U2, ub2, V2, vb2, x3, xb3, nullptr, nullptr, nullptr, N);

        // ---- layer 3 ----
        gatherM_kernel<<<nwBlocks, 256, 0, stream>>>(xb3, ea_t, src_d, rowptr, Hb, N, E, Epad);
        wconv_kernel<<<8, 256, 0, stream>>>(W3, Bfrag, KSTEPS, KD, CC);
        hgemm_kernel<KSTEPS><<<gmBlocks, 256, 0, stream>>>(Hb, Bfrag, acc, N);
        epilogue_kernel<CC, true><<<epBlocks, 256, 0, stream>>>(
            acc, b3, x3, U3, ub3, V3, vb3, nullptr, nullptr, fc2w, fc2b, (float*)d_out, N);
    } else {
        // ---- fallback: unsorted atomic path ----
        float* XW = (float*)ea_d;  // reuse tail region (needs N*K*C1 f32 = 64 MB)
        const int egBlocks = (int)(((size_t)E * 32 + 255) / 256);
        const int xwBlocks = (N + 7) / 8;
        const size_t accBytes = (size_t)N * C1 * sizeof(float);

        hipMemsetAsync(acc, 0, accBytes, stream);
        edge1_kernel<<<egBlocks, 256, 0, stream>>>(x, W1, ea, srcp, dstp, acc, E);
        epilogue_kernel<1, false><<<epBlocks, 256, 0, stream>>>(
            acc, b1, x, U1, ub1, V1, vb1, x2, xb2, nullptr, nullptr, nullptr, N);

        hipMemsetAsync(acc, 0, accBytes, stream);
        xw_kernel<CC><<<xwBlocks, 256, 0, stream>>>(x2, W2, XW, N);
        edge_kernel<<<egBlocks, 256, 0, stream>>>(XW, ea, srcp, dstp, acc, E);
        epilogue_kernel<CC, false><<<epBlocks, 256, 0, stream>>>(
            acc, b2, x2, U2, ub2, V2, vb2, x3, xb3, nullptr, nullptr, nullptr, N);

        hipMemsetAsync(acc, 0, accBytes, stream);
        xw_kernel<CC><<<xwBlocks, 256, 0, stream>>>(x3, W3, XW, N);
        edge_kernel<<<egBlocks, 256, 0, stream>>>(XW, ea, srcp, dstp, acc, E);
        epilogue_kernel<CC, true><<<epBlocks, 256, 0, stream>>>(
            acc, b3, x3, U3, ub3, V3, vb3, nullptr, nullptr, fc2w, fc2b, (float*)d_out, N);
    }
}